// Round 5
// baseline (5102.716 us; speedup 1.0000x reference)
//
#include <hip/hip_runtime.h>

#define BB 128   // batch
#define SS 128   // seq
#define EE 256   // enc dim
#define DD 256   // lstm hidden
#define OO 64    // out dim

// bf16 weight buffer layout (ushort offsets) inside d_out scratch
#define W1_OFF   0         // 768*256   = 196608 (rows: Wh|Wc|We)
#define WHH_OFF  196608    // 256*1024  = 262144
#define WIH_OFF  458752    // 64*1024   = 65536
#define FCW_OFF  524288    // 320*64    = 20480
#define WTOTAL   544768

__device__ __forceinline__ float fsig(float x) { return 1.0f / (1.0f + __expf(-x)); }
__device__ __forceinline__ float ftanh(float x) {
    float t = __expf(-2.0f * fabsf(x));
    float r = (1.0f - t) / (1.0f + t);
    return copysignf(r, x);
}
// swizzle within 32-float groups: conflict-free strided access in P2
__device__ __forceinline__ int SWZ(int e) { return (e & ~31) | ((e + 4 * (e >> 5)) & 31); }

__device__ __forceinline__ unsigned short bf16r(float f) {
    unsigned int u = __float_as_uint(f);
    u = (u + 0x7fffu + ((u >> 16) & 1u)) >> 16;
    return (unsigned short)u;
}

__device__ __forceinline__ void fma8(const uint4 w, const float xv, float* acc) {
    acc[0] += xv * __uint_as_float(w.x << 16);
    acc[1] += xv * __uint_as_float(w.x & 0xffff0000u);
    acc[2] += xv * __uint_as_float(w.y << 16);
    acc[3] += xv * __uint_as_float(w.y & 0xffff0000u);
    acc[4] += xv * __uint_as_float(w.z << 16);
    acc[5] += xv * __uint_as_float(w.z & 0xffff0000u);
    acc[6] += xv * __uint_as_float(w.w << 16);
    acc[7] += xv * __uint_as_float(w.w & 0xffff0000u);
}

// fp32 -> bf16 (RNE) weight conversion, runs every launch (graph-safe, same work)
__global__ __launch_bounds__(256) void conv_kernel(
    const float* __restrict__ W1, const float* __restrict__ Whh,
    const float* __restrict__ Wih, const float* __restrict__ fcW,
    unsigned short* __restrict__ out)
{
    const int idx = blockIdx.x * 256 + threadIdx.x;
    float f;
    if      (idx < WHH_OFF)  f = W1[idx];
    else if (idx < WIH_OFF)  f = Whh[idx - WHH_OFF];
    else if (idx < FCW_OFF)  f = Wih[idx - WIH_OFF];
    else if (idx < WTOTAL)   f = fcW[idx - FCW_OFF];
    else return;
    out[idx] = bf16r(f);
}

// One block (1024 thr, 16 waves) per batch row; whole scan block-local.
// Steady-state loop touches ONLY bf16 weights in global (L2-resident);
// inp/yhist live in LDS as bf16.
__global__ __launch_bounds__(1024, 4) void scan_kernel(
    const float* __restrict__ inp,   // B,S,E
    const float* __restrict__ yhist, // B,S,OO
    const float* __restrict__ h0, const float* __restrict__ c0,
    const float* __restrict__ W1f,   // fp32 W1 (only We rows used, init)
    const float* __restrict__ b1, const float* __restrict__ w2, const float* __restrict__ b2,
    const float* __restrict__ bih, const float* __restrict__ bhh,
    const float* __restrict__ fcb,
    const unsigned short* __restrict__ wbf,  // bf16 weights (see *_OFF)
    float* __restrict__ hctxT)       // ws: [512][128] (0..255 h, 256..511 ctx)
{
    __shared__ float sh_h[DD], sh_c[DD], sh_hc[EE];      // sh_hc SWZ'd
    __shared__ float sh_w2[EE];                          // SWZ'd
    __shared__ float sh_raw[SS];                         // exp(scores)
    __shared__ float sh_ctx[EE], sh_yt[OO];
    __shared__ float sh_misc[1];
    __shared__ float red1[32 * 256];                     // 32 KB
    __shared__ float red2[8 * 1024];                     // 32 KB
    __shared__ unsigned short sh_inp[SS * EE];           // 64 KB bf16
    __shared__ unsigned short sh_yh[SS * OO];            // 16 KB bf16

    const int b = blockIdx.x, t = threadIdx.x;
    const float* inp_b = inp + b * SS * EE;
    const float* yh_b  = yhist + b * SS * OO;
    const unsigned short* W1bf  = wbf + W1_OFF;
    const unsigned short* Whhbf = wbf + WHH_OFF;
    const unsigned short* Wihbf = wbf + WIH_OFF;
    const unsigned short* fcWbf = wbf + FCW_OFF;
    const float b2v = b2[0];

    // per-thread constants (were LDS in round 4 — freed for sh_inp/sh_yh)
    const float bs_reg  = bih[t] + bhh[t];
    const float b1_reg  = (t < 256) ? b1[t] : 0.f;
    const float fcb_reg = (t < 64) ? fcb[t] : 0.f;

    // role constants
    const int e8  = (t & 31) * 8,  kc1 = t >> 5;   // P1
    const int j8  = (t & 127) * 8, kc2 = t >> 7;   // P1b / P4
    const int s_own = t >> 3,      a2  = t & 7, e0 = a2 * 32;  // P2
    const int e4  = (t & 63) * 4,  sc  = t >> 6;   // P3
    const int o4  = (t & 15) * 4,  kc3 = t >> 4;   // P3b

    if (t < 256) {
        sh_h[t] = h0[b * 256 + t]; sh_c[t] = c0[b * 256 + t];
        sh_w2[SWZ(t)] = w2[t];
    }

    // ---- one-time: inp row -> LDS bf16, yhist row -> LDS bf16 ----
    #pragma unroll
    for (int i = 0; i < 8; ++i) {
        const int idx4 = t + i * 1024;           // float4 index 0..8191
        float4 v = *(const float4*)(inp_b + idx4 * 4);
        unsigned int p0 = (unsigned int)bf16r(v.x) | ((unsigned int)bf16r(v.y) << 16);
        unsigned int p1 = (unsigned int)bf16r(v.z) | ((unsigned int)bf16r(v.w) << 16);
        *(uint2*)&sh_inp[idx4 * 4] = make_uint2(p0, p1);
    }
    #pragma unroll
    for (int i = 0; i < 2; ++i) {
        const int idx4 = t + i * 1024;           // float4 index 0..2047
        float4 v = *(const float4*)(yh_b + idx4 * 4);
        unsigned int p0 = (unsigned int)bf16r(v.x) | ((unsigned int)bf16r(v.y) << 16);
        unsigned int p1 = (unsigned int)bf16r(v.z) | ((unsigned int)bf16r(v.w) << 16);
        *(uint2*)&sh_yh[idx4 * 4] = make_uint2(p0, p1);
    }

    // ---- enc_proj into registers via LDS-staged chunks (fp32 We, one-time) ----
    float er[32];
    #pragma unroll
    for (int j = 0; j < 32; ++j) er[j] = 0.f;
    {
        const float* We = W1f + 512 * 256;
        for (int kc = 0; kc < 16; ++kc) {
            {   // stage We rows [kc*16,+16) x 256 -> red1[0..4095]
                const int row = t >> 6, c4 = (t & 63) * 4;
                float4 v = *(const float4*)(We + (size_t)(kc * 16 + row) * 256 + c4);
                *(float4*)&red1[row * 256 + c4] = v;
            }
            {   // stage inp cols [kc*16,+16) for all 128 s -> red1[4096..6143]
                const int s = t >> 3, k2 = (t & 7) * 2;
                float2 v = *(const float2*)(inp_b + s * 256 + kc * 16 + k2);
                red1[4096 + s * 16 + k2] = v.x;
                red1[4096 + s * 16 + k2 + 1] = v.y;
            }
            __syncthreads();
            for (int k = 0; k < 16; ++k) {
                const float xv = red1[4096 + s_own * 16 + k];
                #pragma unroll
                for (int j4 = 0; j4 < 8; ++j4) {
                    float4 w = *(const float4*)&red1[k * 256 + e0 + j4 * 4];
                    er[j4*4+0] += xv * w.x; er[j4*4+1] += xv * w.y;
                    er[j4*4+2] += xv * w.z; er[j4*4+3] += xv * w.w;
                }
            }
            __syncthreads();
        }
    }

    float gh_reg;
    for (int ts = 0; ts < SS; ++ts) {
        // ---- P1: hc partials [32][256] -> red1
        {
            float acc[8];
            #pragma unroll
            for (int r = 0; r < 8; ++r) acc[r] = 0.f;
            #pragma unroll 4
            for (int k = kc1 * 16; k < kc1 * 16 + 16; ++k) {
                const float xv = (k < 256) ? sh_h[k] : sh_c[k - 256];
                uint4 w = *(const uint4*)(W1bf + (size_t)k * 256 + e8);
                fma8(w, xv, acc);
            }
            *(float4*)&red1[kc1 * 256 + e8]     = make_float4(acc[0], acc[1], acc[2], acc[3]);
            *(float4*)&red1[kc1 * 256 + e8 + 4] = make_float4(acc[4], acc[5], acc[6], acc[7]);
        }
        // ---- P1b: gh partials [8][1024] -> red2
        {
            float acc[8];
            #pragma unroll
            for (int r = 0; r < 8; ++r) acc[r] = 0.f;
            #pragma unroll 4
            for (int k = kc2 * 32; k < kc2 * 32 + 32; ++k) {
                const float hv = sh_h[k];
                uint4 w = *(const uint4*)(Whhbf + (size_t)k * 1024 + j8);
                fma8(w, hv, acc);
            }
            *(float4*)&red2[kc2 * 1024 + j8]     = make_float4(acc[0], acc[1], acc[2], acc[3]);
            *(float4*)&red2[kc2 * 1024 + j8 + 4] = make_float4(acc[4], acc[5], acc[6], acc[7]);
        }
        __syncthreads();
        if (t < 256) {
            float v = b1_reg;
            #pragma unroll 8
            for (int kc = 0; kc < 32; ++kc) v += red1[kc * 256 + t];
            sh_hc[SWZ(t)] = v;
        }
        {
            float v = 0.f;
            #pragma unroll
            for (int kc = 0; kc < 8; ++kc) v += red2[kc * 1024 + t];
            gh_reg = v;   // register; red2 reused by P4
        }
        __syncthreads();

        // ---- P2: scores from register er + swizzled hc/w2 (conflict-free)
        {
            float acc = 0.f;
            #pragma unroll
            for (int j4 = 0; j4 < 8; ++j4) {
                const int phys = e0 + ((j4 * 4 + 4 * a2) & 31);
                float4 hc4 = *(const float4*)&sh_hc[phys];
                float4 w24 = *(const float4*)&sh_w2[phys];
                acc += ftanh(er[j4*4+0] + hc4.x) * w24.x;
                acc += ftanh(er[j4*4+1] + hc4.y) * w24.y;
                acc += ftanh(er[j4*4+2] + hc4.z) * w24.z;
                acc += ftanh(er[j4*4+3] + hc4.w) * w24.w;
            }
            acc += __shfl_xor(acc, 1);
            acc += __shfl_xor(acc, 2);
            acc += __shfl_xor(acc, 4);
            if (a2 == 0) sh_raw[s_own] = __expf(acc + b2v);  // max-free: |score|<=sum|w2|~10
        }
        __syncthreads();
        if (t < 64) {
            float v = sh_raw[t] + sh_raw[t + 64];
            #pragma unroll
            for (int m = 32; m > 0; m >>= 1) v += __shfl_xor(v, m);
            if (t == 0) sh_misc[0] = 1.0f / v;
        }
        __syncthreads();

        // ---- P3: context partials [16][256] -> red1 (inp from LDS bf16)
        {
            float ax = 0.f, ay = 0.f, az = 0.f, aw = 0.f;
            for (int s = sc * 8; s < sc * 8 + 8; ++s) {
                const float al = sh_raw[s];
                uint2 w = *(const uint2*)&sh_inp[s * 256 + e4];
                ax += al * __uint_as_float(w.x << 16);
                ay += al * __uint_as_float(w.x & 0xffff0000u);
                az += al * __uint_as_float(w.y << 16);
                aw += al * __uint_as_float(w.y & 0xffff0000u);
            }
            *(float4*)&red1[sc * 256 + e4] = make_float4(ax, ay, az, aw);
        }
        __syncthreads();
        if (t < 256) {
            float v = 0.f;
            #pragma unroll
            for (int k = 0; k < 16; ++k) v += red1[k * 256 + t];
            v *= sh_misc[0];
            sh_ctx[t] = v;
            if (ts == SS - 1) hctxT[(size_t)(256 + t) * 128 + b] = v;
        }
        __syncthreads();

        // ---- P3b: y_tilde partials [64][64] -> red1 (y from LDS bf16)
        {
            float acc[4] = {0.f, 0.f, 0.f, 0.f};
            for (int kk = kc3 * 5; kk < kc3 * 5 + 5; ++kk) {
                const float val = (kk < 256)
                    ? sh_ctx[kk]
                    : __uint_as_float((unsigned int)sh_yh[ts * 64 + (kk - 256)] << 16);
                uint2 w = *(const uint2*)(fcWbf + kk * 64 + o4);
                acc[0] += val * __uint_as_float(w.x << 16);
                acc[1] += val * __uint_as_float(w.x & 0xffff0000u);
                acc[2] += val * __uint_as_float(w.y << 16);
                acc[3] += val * __uint_as_float(w.y & 0xffff0000u);
            }
            *(float4*)&red1[kc3 * 64 + o4] = make_float4(acc[0], acc[1], acc[2], acc[3]);
        }
        __syncthreads();
        if (t < 64) {
            float v = fcb_reg;
            #pragma unroll 16
            for (int kc = 0; kc < 64; ++kc) v += red1[kc * 64 + t];
            sh_yt[t] = v;
        }
        __syncthreads();

        // ---- P4: gate partials (Wih) [8][1024] -> red2
        {
            float acc[8];
            #pragma unroll
            for (int r = 0; r < 8; ++r) acc[r] = 0.f;
            #pragma unroll
            for (int k = kc2 * 8; k < kc2 * 8 + 8; ++k) {
                const float yv = sh_yt[k];
                uint4 w = *(const uint4*)(Wihbf + (size_t)k * 1024 + j8);
                fma8(w, yv, acc);
            }
            *(float4*)&red2[kc2 * 1024 + j8]     = make_float4(acc[0], acc[1], acc[2], acc[3]);
            *(float4*)&red2[kc2 * 1024 + j8 + 4] = make_float4(acc[4], acc[5], acc[6], acc[7]);
        }
        __syncthreads();
        {
            float v = gh_reg + bs_reg;
            #pragma unroll
            for (int kc = 0; kc < 8; ++kc) v += red2[kc * 1024 + t];
            red1[t] = v;   // gates[1024]
        }
        __syncthreads();
        if (t < 256) {
            const float gi = red1[t], gf = red1[256 + t], gg = red1[512 + t], go = red1[768 + t];
            const float cn = fsig(gf) * sh_c[t] + fsig(gi) * ftanh(gg);
            sh_c[t] = cn;
            const float hn = fsig(go) * ftanh(cn);
            sh_h[t] = hn;
            if (ts == SS - 1) hctxT[(size_t)t * 128 + b] = hn;
        }
        __syncthreads();
    }
}

// out(128 x 8192) = A(128x512, stored transposed AT[512][128]) @ W(512x8192) + bias
__global__ __launch_bounds__(256) void out_gemm(
    const float* __restrict__ AT, const float* __restrict__ W,
    const float* __restrict__ bias, float* __restrict__ out)
{
    __shared__ float Ab[64 * 132];  // [k][m]
    __shared__ float Bb[64 * 32];   // [k][n]
    const int t = threadIdx.x;
    const int nt = blockIdx.x * 32;
    const int n4 = (t & 7) * 4;
    const int m4 = (t >> 3) * 4;
    float acc[4][4];
    #pragma unroll
    for (int i = 0; i < 4; ++i)
        #pragma unroll
        for (int jj = 0; jj < 4; ++jj) acc[i][jj] = 0.f;

    for (int kc = 0; kc < 8; ++kc) {
        #pragma unroll
        for (int i = 0; i < 8; ++i) {
            const int flat4 = i * 256 + t;
            const int row = flat4 >> 5, mm4 = (flat4 & 31) * 4;
            float4 v = *(const float4*)(AT + (size_t)(kc * 64 + row) * 128 + mm4);
            *(float4*)&Ab[row * 132 + mm4] = v;
        }
        #pragma unroll
        for (int i = 0; i < 2; ++i) {
            const int fl = t + i * 256;
            const int k = fl >> 3, nn4 = (fl & 7) * 4;
            *(float4*)&Bb[k * 32 + nn4] =
                *(const float4*)(W + (size_t)(kc * 64 + k) * 8192 + nt + nn4);
        }
        __syncthreads();
        for (int k = 0; k < 64; ++k) {
            const float4 bv = *(const float4*)&Bb[k * 32 + n4];
            const float4 av = *(const float4*)&Ab[k * 132 + m4];
            acc[0][0] += av.x * bv.x; acc[0][1] += av.x * bv.y; acc[0][2] += av.x * bv.z; acc[0][3] += av.x * bv.w;
            acc[1][0] += av.y * bv.x; acc[1][1] += av.y * bv.y; acc[1][2] += av.y * bv.z; acc[1][3] += av.y * bv.w;
            acc[2][0] += av.z * bv.x; acc[2][1] += av.z * bv.y; acc[2][2] += av.z * bv.z; acc[2][3] += av.z * bv.w;
            acc[3][0] += av.w * bv.x; acc[3][1] += av.w * bv.y; acc[3][2] += av.w * bv.z; acc[3][3] += av.w * bv.w;
        }
        __syncthreads();
    }
    const float4 bb = *(const float4*)(bias + nt + n4);
    #pragma unroll
    for (int i = 0; i < 4; ++i) {
        float4 r;
        r.x = acc[i][0] + bb.x; r.y = acc[i][1] + bb.y;
        r.z = acc[i][2] + bb.z; r.w = acc[i][3] + bb.w;
        *(float4*)(out + (size_t)(m4 + i) * 8192 + nt + n4) = r;
    }
}

extern "C" void kernel_launch(void* const* d_in, const int* in_sizes, int n_in,
                              void* d_out, int out_size, void* d_ws, size_t ws_size,
                              hipStream_t stream) {
    const float* inp = (const float*)d_in[0];
    const float* yh  = (const float*)d_in[1];
    const float* h0  = (const float*)d_in[2];
    const float* c0  = (const float*)d_in[3];
    const float* W1  = (const float*)d_in[4];
    const float* b1  = (const float*)d_in[5];
    const float* w2  = (const float*)d_in[6];
    const float* b2  = (const float*)d_in[7];
    const float* Wih = (const float*)d_in[8];
    const float* Whh = (const float*)d_in[9];
    const float* bih = (const float*)d_in[10];
    const float* bhh = (const float*)d_in[11];
    const float* fcW = (const float*)d_in[12];
    const float* fcb = (const float*)d_in[13];
    const float* foW = (const float*)d_in[14];
    const float* fob = (const float*)d_in[15];

    float* hctxT = (float*)d_ws;                    // 256 KB (proven)
    unsigned short* wbf = (unsigned short*)d_out;   // 1.09 MB bf16 weights in d_out scratch
                                                    // (fully overwritten by out_gemm)

    conv_kernel<<<dim3((WTOTAL + 255) / 256), dim3(256), 0, stream>>>(W1, Whh, Wih, fcW, wbf);
    scan_kernel<<<dim3(BB), dim3(1024), 0, stream>>>(
        inp, yh, h0, c0, W1, b1, w2, b2, bih, bhh, fcb, wbf, hctxT);
    out_gemm<<<dim3(8192 / 32), dim3(256), 0, stream>>>(hctxT, foW, fob, (float*)d_out);
}